// Round 12
// baseline (101.335 us; speedup 1.0000x reference)
//
#include <hip/hip_runtime.h>
#include <math.h>

#define H 2048
#define W 2048
#define K 16
#define P 15
#define WP 2052        // win pitch: W + 4 replicated guard cols (wrapped float4 reads)
#define LDSP 272       // LDS pitch: 256 tile cols + 16 halo cols

typedef float v4 __attribute__((ext_vector_type(4)));
typedef v4 uv4 __attribute__((aligned(4)));   // dword-aligned vector load

// ---- kernel 1: fused 15x15 exclusive box-sum img -> win, LDS-staged ----
// Block = 32-row x 256-col tile, 320 threads, 52 KB LDS (~3 blocks/CU).
// Block (0,0) additionally computes C and the SORTED (by dy,dx; duplicates
// kept) offset list -> gather's k-runs with equal dy hit L1 back-to-back.
__global__ __launch_bounds__(320) void geneo_win(
        const float* __restrict__ img,
        float* __restrict__ win,
        const float* __restrict__ patterns,
        const float* __restrict__ vectors,
        float* __restrict__ consts,
        int* __restrict__ offs) {
    // slot s (s=1..47) holds img row r0-16+s; the vertical walk overwrites
    // slot ii with colsum row r0+ii (slot ii's img row is dead by then).
    __shared__ float sl[48][LDSP];   // 52,224 B
    __shared__ float psum[5];
    int t  = threadIdx.x;
    int c0 = blockIdx.x * 256;
    int r0 = blockIdx.y * 32;

    // --- consts + sorted offsets (block (0,0) only) ---
    if (blockIdx.x == 0 && blockIdx.y == 0) {
        float ps = 0.f;
        for (int idx = t; idx < 900; idx += 320) {      // 900 v4 = 3600 floats
            v4 v = *(const v4*)&patterns[idx * 4];
            ps += (v.x + v.y) + (v.z + v.w);
        }
        #pragma unroll
        for (int q = 32; q > 0; q >>= 1) ps += __shfl_down(ps, q, 64);
        if ((t & 63) == 0) psum[t >> 6] = ps;
        if (t == 64) {   // one lane: insertion sort by (dy,dx), duplicates kept
            int oy[K], ox[K];
            for (int k = 0; k < K; ++k) {
                oy[k] = (int)floorf(vectors[2 * k]);
                ox[k] = (int)floorf(vectors[2 * k + 1]);
            }
            for (int a = 1; a < K; ++a) {
                int y = oy[a], x = ox[a], b = a - 1;
                while (b >= 0 && (oy[b] > y || (oy[b] == y && ox[b] > x))) {
                    oy[b + 1] = oy[b]; ox[b + 1] = ox[b]; --b;
                }
                oy[b + 1] = y; ox[b + 1] = x;
            }
            for (int k = 0; k < K; ++k) {
                offs[2 * k] = oy[k]; offs[2 * k + 1] = ox[k];
            }
        }
        __syncthreads();
        if (t == 0) {
            float total = ((psum[0] + psum[1]) + (psum[2] + psum[3])) + psum[4];
            consts[0] = (16.0f - total * (1.0f / 225.0f)) * (1.0f / 15.0f);
        }
    }

    // --- stage img rows [r0-15, r0+32) x cols [c0-16, c0+256) into LDS ---
    for (int idx = t; idx < 47 * 68; idx += 320) {
        int q = idx / 68;                 // 0..46 -> img row r0-15+q -> slot q+1
        int c = idx - q * 68;             // v4 col group
        int grow = r0 - 15 + q;
        int gcol = c0 - 16 + 4 * c;
        v4 v = {0.f, 0.f, 0.f, 0.f};
        if (grow >= 0 && gcol >= 0)       // zero-pad (gcol<0 => whole v4 < 0)
            v = *(const v4*)&img[grow * W + gcol];
        *(v4*)&sl[q + 1][4 * c] = v;
    }
    __syncthreads();

    // --- vertical running sum in LDS (one column/thread, stride-1 lanes) ---
    if (t < LDSP) {
        float s = 0.f;
        #pragma unroll
        for (int q = 1; q <= 15; ++q) s += sl[q][t];     // rows r0-15..r0-1
        #pragma unroll
        for (int ii = 0; ii < 32; ++ii) {
            float sv = s;
            s += sl[ii + 16][t] - sl[ii + 1][t];         // +row r0+ii, -row r0+ii-15
            sl[ii][t] = sv;                              // colsum row r0+ii
        }
    }
    __syncthreads();

    // --- phase B: horizontal 15-tap, 4 cols/thread via 5 aligned ds_read_b128 ---
    // output cols c0+4g..c0+4g+3 need lds cols 4g+1..4g+18 (subset of [4g,4g+20))
    if (t < 256) {
        int g  = t & 63;                  // col group
        int rb = (t >> 6) * 8;            // 8 rows per thread
        #pragma unroll
        for (int rr = 0; rr < 8; ++rr) {
            int ii = rb + rr;
            const float* row = &sl[ii][4 * g];
            v4 V0 = *(const v4*)&row[0];
            v4 V1 = *(const v4*)&row[4];
            v4 V2 = *(const v4*)&row[8];
            v4 V3 = *(const v4*)&row[12];
            v4 V4 = *(const v4*)&row[16];
            float s0 = ((V0.y + V0.z) + (V0.w + V1.x))
                     + ((V1.y + V1.z) + (V1.w + V2.x))
                     + ((V2.y + V2.z) + (V2.w + V3.x))
                     + ((V3.y + V3.z) + V3.w);
            float s1 = s0 - V0.y + V4.x;
            float s2 = s1 - V0.z + V4.y;
            float s3 = s2 - V0.w + V4.z;
            v4 r4 = {s0, s1, s2, s3};
            int gi = r0 + ii;
            *(v4*)&win[gi * WP + c0 + 4 * g] = r4;
            if (c0 == 0 && g == 0)        // guard cols 2048..2051 = cols 0..3
                *(v4*)&win[gi * WP + 2048] = r4;
        }
    }
}

// ---- kernel 2: 16-way circular-shift gather-sum, XCD-banded, 8 out/thread ----
// (byte-for-byte R8 structure; offsets arrive sorted by (dy,dx) for L1 reuse)
__global__ __launch_bounds__(256) void geneo_gather(
        const float* __restrict__ win,
        const float* __restrict__ consts,
        const int* __restrict__ offs,
        float* __restrict__ out) {
    __shared__ int soy[K], sox[K];
    __shared__ float sC;
    int t = threadIdx.x;
    if (t < K) { soy[t] = offs[t * 2]; sox[t] = offs[t * 2 + 1]; }
    if (t == 0) sC = consts[0];
    __syncthreads();

    // round-robin d%8 XCD assignment: XCD x gets rows [x*256, x*256+256)
    // -> its win band (~2.1 MB) fits the 4 MiB per-XCD L2
    int d = blockIdx.x;              // 2048 blocks, one output row each
    int i = ((d & 7) << 8) | (d >> 3);
    int j = 4 * t;                   // cols j and j+1024 per thread

    const float S = 1.0f / 3375.0f;  // 1/(p^2 (K-1)), data-independent
    v4 acc0 = {0.f, 0.f, 0.f, 0.f};
    v4 acc1 = {0.f, 0.f, 0.f, 0.f};
    #pragma unroll
    for (int k = 0; k < K; ++k) {    // MUST stay compile-time unrolled (R9 lesson)
        int ri = (i - soy[k]) & (H - 1);
        int rj = (j - sox[k]) & (W - 1);
        const float* row = &win[ri * WP];
        acc0 += *(const uv4*)&row[rj];
        acc1 += *(const uv4*)&row[rj ^ 1024];   // (rj+1024) mod 2048
    }
    v4 o0 = acc0 * S + sC;
    v4 o1 = acc1 * S + sC;
    *(v4*)&out[i * W + j]        = o0;
    *(v4*)&out[i * W + j + 1024] = o1;
}

extern "C" void kernel_launch(void* const* d_in, const int* in_sizes, int n_in,
                              void* d_out, int out_size, void* d_ws, size_t ws_size,
                              hipStream_t stream) {
    const float* x        = (const float*)d_in[0]; // (1,1,H,W)
    const float* patterns = (const float*)d_in[1]; // (K,P,P)
    const float* vectors  = (const float*)d_in[2]; // (K,2)
    float* out = (float*)d_out;

    float* win    = (float*)d_ws;          // H*WP floats
    float* consts = win + H * WP;          // 1 float
    int*   offs   = (int*)(consts + 1);    // 2K ints (oy,ox pairs)

    geneo_win<<<dim3(8, 64), 320, 0, stream>>>(x, win, patterns, vectors, consts, offs);
    geneo_gather<<<2048, 256, 0, stream>>>(win, consts, offs, out);
}

// Round 13
// 90.023 us; speedup vs baseline: 1.1257x; 1.1257x over previous
//
#include <hip/hip_runtime.h>
#include <math.h>

#define H 2048
#define W 2048
#define K 16
#define P 15
#define WP 2052        // win pitch: W + 4 replicated guard cols (wrapped float4 reads)
#define LDSP 272       // LDS pitch: 256 tile cols + 16 halo cols

typedef float v4 __attribute__((ext_vector_type(4)));
typedef v4 uv4 __attribute__((aligned(4)));   // dword-aligned vector load

// ---- kernel 1: fused 15x15 exclusive box-sum img -> win, LDS-staged ----
// Block = 32-row x 256-col tile, 320 threads, 52 KB LDS (~3 blocks/CU).
// Block (0,0) additionally computes C and integer offsets into ws.
// NOTE (R7/R9/R12): do NOT sort/dedup the offsets — unsorted order is ~11 us
// faster (sorted k-runs hotspot the same win row grid-wide).
__global__ __launch_bounds__(320) void geneo_win(
        const float* __restrict__ img,
        float* __restrict__ win,
        const float* __restrict__ patterns,
        const float* __restrict__ vectors,
        float* __restrict__ consts,
        int* __restrict__ offs) {
    // slot s (s=1..47) holds img row r0-16+s; the vertical walk overwrites
    // slot ii with colsum row r0+ii (slot ii's img row is dead by then).
    __shared__ float sl[48][LDSP];   // 52,224 B
    __shared__ float psum[5];
    int t  = threadIdx.x;
    int c0 = blockIdx.x * 256;
    int r0 = blockIdx.y * 32;

    // --- consts (block (0,0) only) ---
    if (blockIdx.x == 0 && blockIdx.y == 0) {
        float ps = 0.f;
        for (int idx = t; idx < 900; idx += 320) {      // 900 v4 = 3600 floats
            v4 v = *(const v4*)&patterns[idx * 4];
            ps += (v.x + v.y) + (v.z + v.w);
        }
        #pragma unroll
        for (int q = 32; q > 0; q >>= 1) ps += __shfl_down(ps, q, 64);
        if ((t & 63) == 0) psum[t >> 6] = ps;
        if (t < 2 * K) offs[t] = (int)floorf(vectors[t]);
        __syncthreads();
        if (t == 0) {
            float total = ((psum[0] + psum[1]) + (psum[2] + psum[3])) + psum[4];
            consts[0] = (16.0f - total * (1.0f / 225.0f)) * (1.0f / 15.0f);
        }
    }

    // --- stage img rows [r0-15, r0+32) x cols [c0-16, c0+256) into LDS ---
    for (int idx = t; idx < 47 * 68; idx += 320) {
        int q = idx / 68;                 // 0..46 -> img row r0-15+q -> slot q+1
        int c = idx - q * 68;             // v4 col group
        int grow = r0 - 15 + q;
        int gcol = c0 - 16 + 4 * c;
        v4 v = {0.f, 0.f, 0.f, 0.f};
        if (grow >= 0 && gcol >= 0)       // zero-pad (gcol<0 => whole v4 < 0)
            v = *(const v4*)&img[grow * W + gcol];
        *(v4*)&sl[q + 1][4 * c] = v;
    }
    __syncthreads();

    // --- vertical running sum in LDS (one column/thread, stride-1 lanes) ---
    if (t < LDSP) {
        float s = 0.f;
        #pragma unroll
        for (int q = 1; q <= 15; ++q) s += sl[q][t];     // rows r0-15..r0-1
        #pragma unroll
        for (int ii = 0; ii < 32; ++ii) {
            float sv = s;
            s += sl[ii + 16][t] - sl[ii + 1][t];         // +row r0+ii, -row r0+ii-15
            sl[ii][t] = sv;                              // colsum row r0+ii
        }
    }
    __syncthreads();

    // --- phase B: horizontal 15-tap, 4 cols/thread via 5 aligned ds_read_b128 ---
    // output cols c0+4g..c0+4g+3 need lds cols 4g+1..4g+18 (subset of [4g,4g+20))
    if (t < 256) {
        int g  = t & 63;                  // col group
        int rb = (t >> 6) * 8;            // 8 rows per thread
        #pragma unroll
        for (int rr = 0; rr < 8; ++rr) {
            int ii = rb + rr;
            const float* row = &sl[ii][4 * g];
            v4 V0 = *(const v4*)&row[0];
            v4 V1 = *(const v4*)&row[4];
            v4 V2 = *(const v4*)&row[8];
            v4 V3 = *(const v4*)&row[12];
            v4 V4 = *(const v4*)&row[16];
            float s0 = ((V0.y + V0.z) + (V0.w + V1.x))
                     + ((V1.y + V1.z) + (V1.w + V2.x))
                     + ((V2.y + V2.z) + (V2.w + V3.x))
                     + ((V3.y + V3.z) + V3.w);
            float s1 = s0 - V0.y + V4.x;
            float s2 = s1 - V0.z + V4.y;
            float s3 = s2 - V0.w + V4.z;
            v4 r4 = {s0, s1, s2, s3};
            int gi = r0 + ii;
            *(v4*)&win[gi * WP + c0 + 4 * g] = r4;
            if (c0 == 0 && g == 0)        // guard cols 2048..2051 = cols 0..3
                *(v4*)&win[gi * WP + 2048] = r4;
        }
    }
}

// ---- kernel 2: 16-way circular-shift gather-sum, XCD-banded, 8 out/thread ----
__global__ __launch_bounds__(256) void geneo_gather(
        const float* __restrict__ win,
        const float* __restrict__ consts,
        const int* __restrict__ offs,
        float* __restrict__ out) {
    __shared__ int soy[K], sox[K];
    __shared__ float sC;
    int t = threadIdx.x;
    if (t < K) { soy[t] = offs[t * 2]; sox[t] = offs[t * 2 + 1]; }
    if (t == 0) sC = consts[0];
    __syncthreads();

    // round-robin d%8 XCD assignment: XCD x gets rows [x*256, x*256+256)
    // -> its win band (~2.1 MB) fits the 4 MiB per-XCD L2
    int d = blockIdx.x;              // 2048 blocks, one output row each
    int i = ((d & 7) << 8) | (d >> 3);
    int j = 4 * t;                   // cols j and j+1024 per thread

    const float S = 1.0f / 3375.0f;  // 1/(p^2 (K-1)), data-independent
    v4 acc0 = {0.f, 0.f, 0.f, 0.f};
    v4 acc1 = {0.f, 0.f, 0.f, 0.f};
    #pragma unroll
    for (int k = 0; k < K; ++k) {    // MUST stay compile-time unrolled (R9 lesson)
        int ri = (i - soy[k]) & (H - 1);
        int rj = (j - sox[k]) & (W - 1);
        const float* row = &win[ri * WP];
        acc0 += *(const uv4*)&row[rj];
        acc1 += *(const uv4*)&row[rj ^ 1024];   // (rj+1024) mod 2048
    }
    v4 o0 = acc0 * S + sC;
    v4 o1 = acc1 * S + sC;
    *(v4*)&out[i * W + j]        = o0;
    *(v4*)&out[i * W + j + 1024] = o1;
}

extern "C" void kernel_launch(void* const* d_in, const int* in_sizes, int n_in,
                              void* d_out, int out_size, void* d_ws, size_t ws_size,
                              hipStream_t stream) {
    const float* x        = (const float*)d_in[0]; // (1,1,H,W)
    const float* patterns = (const float*)d_in[1]; // (K,P,P)
    const float* vectors  = (const float*)d_in[2]; // (K,2)
    float* out = (float*)d_out;

    float* win    = (float*)d_ws;          // H*WP floats
    float* consts = win + H * WP;          // 1 float
    int*   offs   = (int*)(consts + 1);    // 2K ints (oy,ox pairs)

    geneo_win<<<dim3(8, 64), 320, 0, stream>>>(x, win, patterns, vectors, consts, offs);
    geneo_gather<<<2048, 256, 0, stream>>>(win, consts, offs, out);
}

// Round 14
// 89.987 us; speedup vs baseline: 1.1261x; 1.0004x over previous
//
#include <hip/hip_runtime.h>
#include <math.h>

#define H 2048
#define W 2048
#define K 16
#define P 15
#define WP 2052        // win pitch: W + 4 replicated guard cols (wrapped float4 reads)
#define LDSP 272       // LDS pitch: 256 tile cols + 16 halo cols

typedef float v4 __attribute__((ext_vector_type(4)));
typedef v4 uv4 __attribute__((aligned(4)));   // dword-aligned vector load

// ---- kernel 1: fused 15x15 exclusive box-sum img -> win, LDS-staged ----
// Block = 32-row x 256-col tile, 320 threads, 52 KB LDS (~3 blocks/CU).
// Block (0,0) additionally computes C and integer offsets into ws.
// NOTE (R7/R9/R12): do NOT sort/dedup the offsets — unsorted order is ~11 us
// faster (sorted k-runs hotspot the same win row grid-wide).
__global__ __launch_bounds__(320) void geneo_win(
        const float* __restrict__ img,
        float* __restrict__ win,
        const float* __restrict__ patterns,
        const float* __restrict__ vectors,
        float* __restrict__ consts,
        int* __restrict__ offs) {
    // slot s (s=1..47) holds img row r0-16+s; the vertical walk overwrites
    // slot ii with colsum row r0+ii (slot ii's img row is dead by then).
    __shared__ float sl[48][LDSP];   // 52,224 B
    __shared__ float psum[5];
    int t  = threadIdx.x;
    int c0 = blockIdx.x * 256;
    int r0 = blockIdx.y * 32;

    // --- consts (block (0,0) only) ---
    if (blockIdx.x == 0 && blockIdx.y == 0) {
        float ps = 0.f;
        for (int idx = t; idx < 900; idx += 320) {      // 900 v4 = 3600 floats
            v4 v = *(const v4*)&patterns[idx * 4];
            ps += (v.x + v.y) + (v.z + v.w);
        }
        #pragma unroll
        for (int q = 32; q > 0; q >>= 1) ps += __shfl_down(ps, q, 64);
        if ((t & 63) == 0) psum[t >> 6] = ps;
        if (t < 2 * K) offs[t] = (int)floorf(vectors[t]);
        __syncthreads();
        if (t == 0) {
            float total = ((psum[0] + psum[1]) + (psum[2] + psum[3])) + psum[4];
            consts[0] = (16.0f - total * (1.0f / 225.0f)) * (1.0f / 15.0f);
        }
    }

    // --- stage img rows [r0-15, r0+32) x cols [c0-16, c0+256) into LDS ---
    for (int idx = t; idx < 47 * 68; idx += 320) {
        int q = idx / 68;                 // 0..46 -> img row r0-15+q -> slot q+1
        int c = idx - q * 68;             // v4 col group
        int grow = r0 - 15 + q;
        int gcol = c0 - 16 + 4 * c;
        v4 v = {0.f, 0.f, 0.f, 0.f};
        if (grow >= 0 && gcol >= 0)       // zero-pad (gcol<0 => whole v4 < 0)
            v = *(const v4*)&img[grow * W + gcol];
        *(v4*)&sl[q + 1][4 * c] = v;
    }
    __syncthreads();

    // --- vertical running sum in LDS (one column/thread, stride-1 lanes) ---
    if (t < LDSP) {
        float s = 0.f;
        #pragma unroll
        for (int q = 1; q <= 15; ++q) s += sl[q][t];     // rows r0-15..r0-1
        #pragma unroll
        for (int ii = 0; ii < 32; ++ii) {
            float sv = s;
            s += sl[ii + 16][t] - sl[ii + 1][t];         // +row r0+ii, -row r0+ii-15
            sl[ii][t] = sv;                              // colsum row r0+ii
        }
    }
    __syncthreads();

    // --- phase B: horizontal 15-tap, 4 cols/thread via 5 aligned ds_read_b128 ---
    // output cols c0+4g..c0+4g+3 need lds cols 4g+1..4g+18 (subset of [4g,4g+20))
    if (t < 256) {
        int g  = t & 63;                  // col group
        int rb = (t >> 6) * 8;            // 8 rows per thread
        #pragma unroll
        for (int rr = 0; rr < 8; ++rr) {
            int ii = rb + rr;
            const float* row = &sl[ii][4 * g];
            v4 V0 = *(const v4*)&row[0];
            v4 V1 = *(const v4*)&row[4];
            v4 V2 = *(const v4*)&row[8];
            v4 V3 = *(const v4*)&row[12];
            v4 V4 = *(const v4*)&row[16];
            float s0 = ((V0.y + V0.z) + (V0.w + V1.x))
                     + ((V1.y + V1.z) + (V1.w + V2.x))
                     + ((V2.y + V2.z) + (V2.w + V3.x))
                     + ((V3.y + V3.z) + V3.w);
            float s1 = s0 - V0.y + V4.x;
            float s2 = s1 - V0.z + V4.y;
            float s3 = s2 - V0.w + V4.z;
            v4 r4 = {s0, s1, s2, s3};
            int gi = r0 + ii;
            *(v4*)&win[gi * WP + c0 + 4 * g] = r4;
            if (c0 == 0 && g == 0)        // guard cols 2048..2051 = cols 0..3
                *(v4*)&win[gi * WP + 2048] = r4;
        }
    }
}

// ---- kernel 2: 16-way circular-shift gather-sum, XCD-banded, 8 out/thread ----
// out stores are nontemporal (nt): out lines are never re-read, and without
// the hint they compete with the ~2.1 MB win band for the 4 MiB per-XCD L2.
__global__ __launch_bounds__(256) void geneo_gather(
        const float* __restrict__ win,
        const float* __restrict__ consts,
        const int* __restrict__ offs,
        float* __restrict__ out) {
    __shared__ int soy[K], sox[K];
    __shared__ float sC;
    int t = threadIdx.x;
    if (t < K) { soy[t] = offs[t * 2]; sox[t] = offs[t * 2 + 1]; }
    if (t == 0) sC = consts[0];
    __syncthreads();

    // round-robin d%8 XCD assignment: XCD x gets rows [x*256, x*256+256)
    // -> its win band (~2.1 MB) fits the 4 MiB per-XCD L2
    int d = blockIdx.x;              // 2048 blocks, one output row each
    int i = ((d & 7) << 8) | (d >> 3);
    int j = 4 * t;                   // cols j and j+1024 per thread

    const float S = 1.0f / 3375.0f;  // 1/(p^2 (K-1)), data-independent
    v4 acc0 = {0.f, 0.f, 0.f, 0.f};
    v4 acc1 = {0.f, 0.f, 0.f, 0.f};
    #pragma unroll
    for (int k = 0; k < K; ++k) {    // MUST stay compile-time unrolled (R9 lesson)
        int ri = (i - soy[k]) & (H - 1);
        int rj = (j - sox[k]) & (W - 1);
        const float* row = &win[ri * WP];
        acc0 += *(const uv4*)&row[rj];
        acc1 += *(const uv4*)&row[rj ^ 1024];   // (rj+1024) mod 2048
    }
    v4 o0 = acc0 * S + sC;
    v4 o1 = acc1 * S + sC;
    __builtin_nontemporal_store(o0, (v4*)&out[i * W + j]);
    __builtin_nontemporal_store(o1, (v4*)&out[i * W + j + 1024]);
}

extern "C" void kernel_launch(void* const* d_in, const int* in_sizes, int n_in,
                              void* d_out, int out_size, void* d_ws, size_t ws_size,
                              hipStream_t stream) {
    const float* x        = (const float*)d_in[0]; // (1,1,H,W)
    const float* patterns = (const float*)d_in[1]; // (K,P,P)
    const float* vectors  = (const float*)d_in[2]; // (K,2)
    float* out = (float*)d_out;

    float* win    = (float*)d_ws;          // H*WP floats
    float* consts = win + H * WP;          // 1 float
    int*   offs   = (int*)(consts + 1);    // 2K ints (oy,ox pairs)

    geneo_win<<<dim3(8, 64), 320, 0, stream>>>(x, win, patterns, vectors, consts, offs);
    geneo_gather<<<2048, 256, 0, stream>>>(win, consts, offs, out);
}